// Round 28
// baseline (617.978 us; speedup 1.0000x reference)
//
#include <hip/hip_runtime.h>
#include <hip/hip_fp16.h>
#include <math.h>

#define Bn 16
#define Sn 577
#define Dn 1024
#define Hn 16
#define DHn 64
#define Fn 4096
#define NROW (Bn*Sn)   // 9232
#define EPSf 1e-6f

typedef unsigned short u16;
typedef unsigned int u32;
typedef __attribute__((ext_vector_type(8))) _Float16 f16x8;
typedef __attribute__((ext_vector_type(4))) float f32x4;

__device__ inline u16 f2h(float x) { return __half_as_ushort(__float2half(x)); }

// XCD-aware bijective block swizzle (MI355X: 8 XCDs, round-robin dispatch).
__device__ inline void xcd_swizzle(int& bx, int& by) {
    int gx = gridDim.x;
    int nwg = gx * gridDim.y;
    int n = by * gx + bx;
    if ((nwg & 7) == 0) {
        int cpx = nwg >> 3;
        int w = (n & 7) * cpx + (n >> 3);
        bx = w % gx;
        by = w / gx;
    }
}

// ============================================================================
// Fused prologue (R26): weight convert + vtb zeroing + LN1 in ONE dispatch.
// ============================================================================
__device__ inline void conv_tile(const float* __restrict__ W, u16* __restrict__ T16,
                                 int K, int N, int bx, int by) {
    __shared__ float t[32][33];
    int n0 = bx * 32, k0 = by * 32;
    int tx = threadIdx.x & 31, ty = threadIdx.x >> 5;
#pragma unroll
    for (int i = 0; i < 4; i++) {
        int kk = ty * 4 + i;
        t[kk][tx] = W[(size_t)(k0 + kk) * N + n0 + tx];
    }
    __syncthreads();
#pragma unroll
    for (int i = 0; i < 4; i++) {
        int nn = ty * 4 + i;
        T16[(size_t)(n0 + nn) * K + k0 + tx] = f2h(t[tx][nn]);
    }
}

__device__ inline void ln_row_f16(const float* __restrict__ x,
                                  const float* __restrict__ g,
                                  const float* __restrict__ b,
                                  u16* __restrict__ oh, int row) {
    int tid = threadIdx.x;
    const float* xr = x + (size_t)row * Dn;
    float v[4];
    float s = 0.f;
#pragma unroll
    for (int i = 0; i < 4; i++) { v[i] = xr[tid + i * 256]; s += v[i]; }
    __shared__ float red[256];
    red[tid] = s; __syncthreads();
    for (int o = 128; o > 0; o >>= 1) { if (tid < o) red[tid] += red[tid + o]; __syncthreads(); }
    float mean = red[0] * (1.f / Dn);
    __syncthreads();
    float sq = 0.f;
#pragma unroll
    for (int i = 0; i < 4; i++) { float d = v[i] - mean; sq += d * d; }
    red[tid] = sq; __syncthreads();
    for (int o = 128; o > 0; o >>= 1) { if (tid < o) red[tid] += red[tid + o]; __syncthreads(); }
    float rstd = rsqrtf(red[0] * (1.f / Dn) + EPSf);
#pragma unroll
    for (int i = 0; i < 4; i++) {
        int c = tid + i * 256;
        float y = (v[i] - mean) * rstd * g[c] + b[c];
        oh[(size_t)row * Dn + c] = f2h(y);
    }
}

__global__ __launch_bounds__(256) void prep_all(
    const float* __restrict__ wq, const float* __restrict__ wk,
    const float* __restrict__ wv, const float* __restrict__ wo,
    const float* __restrict__ w1, const float* __restrict__ w2,
    const float* __restrict__ x, const float* __restrict__ ln1g,
    const float* __restrict__ ln1b,
    u16* __restrict__ wqkvT, u16* __restrict__ woT,
    u16* __restrict__ w1T, u16* __restrict__ w2T,
    u16* __restrict__ vtb, u16* __restrict__ xn_h)
{
    int t = blockIdx.x;
    if (t < 4096) {
        int which = t >> 10;          // 0=wq 1=wk 2=wv 3=wo
        int t2 = t & 1023;
        int bx = t2 & 31, by = t2 >> 5;
        const float* src = (which == 0) ? wq : (which == 1) ? wk : (which == 2) ? wv : wo;
        u16* dst = (which == 3) ? woT : (wqkvT + (size_t)which * 1024 * 1024);
        conv_tile(src, dst, 1024, 1024, bx, by);
    } else if (t < 8192) {
        int t2 = t - 4096;
        conv_tile(w1, w1T, 1024, 4096, t2 & 127, t2 >> 7);
    } else if (t < 12288) {
        int t2 = t - 8192;
        conv_tile(w2, w2T, 4096, 1024, t2 & 31, t2 >> 5);
    } else if (t < 13568) {
        size_t base = (size_t)(t - 12288) * 16384 + (size_t)threadIdx.x * 16;
        char* p = (char*)vtb + base;
        float4 z = make_float4(0.f, 0.f, 0.f, 0.f);
#pragma unroll
        for (int i = 0; i < 4; i++) *(float4*)(p + (size_t)i * 4096) = z;
    } else {
        ln_row_f16(x, ln1g, ln1b, xn_h, t - 13568);
    }
}

// ============================================================================
// LayerNorm -> fp16 (standalone, used for LN2)
// ============================================================================
__global__ __launch_bounds__(256) void ln_f16(const float* __restrict__ x,
                                              const float* __restrict__ g,
                                              const float* __restrict__ b,
                                              u16* __restrict__ oh) {
    ln_row_f16(x, g, b, oh, blockIdx.x);
}

// fp32-output LN (fallback path)
__global__ __launch_bounds__(256) void ln_kernel(const float* __restrict__ x,
                                                 const float* __restrict__ g,
                                                 const float* __restrict__ b,
                                                 float* __restrict__ out) {
    int row = blockIdx.x;
    int tid = threadIdx.x;
    const float* xr = x + (size_t)row * Dn;
    float v[4];
    float s = 0.f;
#pragma unroll
    for (int i = 0; i < 4; i++) { v[i] = xr[tid + i * 256]; s += v[i]; }
    __shared__ float red[256];
    red[tid] = s; __syncthreads();
    for (int o = 128; o > 0; o >>= 1) { if (tid < o) red[tid] += red[tid + o]; __syncthreads(); }
    float mean = red[0] * (1.f / Dn);
    __syncthreads();
    float sq = 0.f;
#pragma unroll
    for (int i = 0; i < 4; i++) { float d = v[i] - mean; sq += d * d; }
    red[tid] = sq; __syncthreads();
    for (int o = 128; o > 0; o >>= 1) { if (tid < o) red[tid] += red[tid + o]; __syncthreads(); }
    float rstd = rsqrtf(red[0] * (1.f / Dn) + EPSf);
    float* orow = out + (size_t)row * Dn;
#pragma unroll
    for (int i = 0; i < 4; i++) {
        int c = tid + i * 256;
        orow[c] = (v[i] - mean) * rstd * g[c] + b[c];
    }
}

// ============================================================================
// Shared GEMM staging helpers
// ============================================================================
__device__ inline void gld_lds16(const u16* g, u16* l) {
    __builtin_amdgcn_global_load_lds((const __attribute__((address_space(1))) void*)g,
                                     (__attribute__((address_space(3))) void*)l,
                                     16, 0, 0);
}

// ============================================================================
// R28: 8-phase 256x256 fp16 GEMM (T3+T4+T2+T5 combo per the verified m201
// template). 512 thr / 8 waves (2M x 4N, per-wave C = 128x64), BK=64,
// 128KB dynamic LDS = 2 dbuf x [A 256x64 | B 256x64] fp16.
// - XOR-8 chunk swizzle: store chunk c of row r at slot c^(r&7); staging is
//   linear-dest global_load_lds with PRE-SWIZZLED source (m104/m201 rule).
// - Per K-tile: 4 phases {ds_read subtile; 2 glds; s_barrier; setprio(1);
//   16 MFMA; setprio(0); s_barrier}; ONE counted vmcnt(6) per tile (never 0
//   in steady state).
// - Race invariant: each prefetch targets only regions freed by an earlier
//   post-MFMA barrier: B(t) freed after P0 -> B(t+2) staged P1,P2;
//   A-quads 0,1 freed after P1 -> staged P3; quads 2,3 freed after P3 ->
//   staged at (t+1).P0 (other buffer's A1,A3). vmcnt(6)+barrier at tile
//   start certifies all waves' tile-t loads landed.
// EPI: 1 = gelu(+bias) -> fp16 ; 2 = +bias+resid -> fp32
// ============================================================================
template<int EPI>
__global__ __launch_bounds__(512, 2) void gemm_8p(
    const u16* __restrict__ A, const u16* __restrict__ B,
    const float* __restrict__ bias, const float* __restrict__ resid,
    float* __restrict__ Cf, u16* __restrict__ Ch,
    int M, int N, int K)
{
    extern __shared__ u16 dl[];   // [2][32768]: A plane [buf][row*64]; B at +16384
    const int tid = threadIdx.x;
    const int l = tid & 63, w = tid >> 6;          // 8 waves
    const int wr = (w >> 2) * 128, wc = (w & 3) * 64;
    int bx = blockIdx.x, by = blockIdx.y;
    xcd_swizzle(bx, by);
    const int row0 = by * 256, col0 = bx * 256;

    // ---- staging source pointers (pre-swizzled chunk; K-invariant) ----
    const int lr = l >> 3;                     // row-in-8
    const int sw8 = ((l & 7) ^ lr) * 8;        // pre-swizzled k-chunk (u16)
    const u16* pA[4];
    const u16* pB[4];
#pragma unroll
    for (int g = 0; g < 4; g++) {
        int ra = row0 + w * 8 + g * 64 + lr; if (ra > M - 1) ra = M - 1;
        int rb = col0 + w * 8 + g * 64 + lr; if (rb > N - 1) rb = N - 1;
        pA[g] = A + (size_t)ra * K + sw8;
        pB[g] = B + (size_t)rb * K + sw8;
    }

    // issue one wave-level gld: plane 0=A,1=B; g = 64-row group; kt = K-tile
    auto GLD_A = [&](int buf, int g, int kt) {
        gld_lds16(pA[g] + kt * 64, dl + (size_t)buf * 32768 + (w * 8 + g * 64) * 64);
    };
    auto GLD_B = [&](int buf, int g, int kt) {
        gld_lds16(pB[g] + kt * 64, dl + (size_t)buf * 32768 + 16384 + (w * 8 + g * 64) * 64);
    };

    // ---- fragment addressing (u16 units). row&7 == l&7 for all frags. ----
    const int c0 = (((l >> 4) + 0) ^ (l & 7)) * 8;   // ks=0 chunk slot
    const int c1 = (((l >> 4) + 4) ^ (l & 7)) * 8;   // ks=1 chunk slot
    int aoff[8], boff[4];
#pragma unroll
    for (int i = 0; i < 8; i++) aoff[i] = (wr + i * 16 + (l & 15)) * 64;
#pragma unroll
    for (int j = 0; j < 4; j++) boff[j] = 16384 + (wc + j * 16 + (l & 15)) * 64;

    f32x4 acc[8][4];
#pragma unroll
    for (int i = 0; i < 8; i++)
#pragma unroll
        for (int j = 0; j < 4; j++)
            acc[i][j] = (f32x4){0.f, 0.f, 0.f, 0.f};

    const int nk = K / 64;   // 16 for K=1024

    // ---- prologue: tile0 (8 glds), then tile1's B0-3 + A0,A2 (6 glds) ----
#pragma unroll
    for (int g = 0; g < 4; g++) GLD_A(0, g, 0);
#pragma unroll
    for (int g = 0; g < 4; g++) GLD_B(0, g, 0);
#pragma unroll
    for (int g = 0; g < 4; g++) GLD_B(1, g, 1);
    GLD_A(1, 0, 1);
    GLD_A(1, 2, 1);

    f16x8 bf0[4], bf1[4];

    for (int t = 0; t < nk; ++t) {
        const int buf = t & 1;
        const u16* P = dl + (size_t)buf * 32768;

        // tile t's loads complete (6 newest = tile t+1's partial stay in flight)
        if (t == nk - 1) asm volatile("s_waitcnt vmcnt(0)" ::: "memory");
        else             asm volatile("s_waitcnt vmcnt(6)" ::: "memory");
        __builtin_amdgcn_s_barrier();

        // ---------------- phase 0: i=0,1 + all B ----------------
        {
            f16x8 aA0 = *(const f16x8*)(P + aoff[0] + c0);
            f16x8 aA1 = *(const f16x8*)(P + aoff[0] + c1);
            f16x8 aB0 = *(const f16x8*)(P + aoff[1] + c0);
            f16x8 aB1 = *(const f16x8*)(P + aoff[1] + c1);
#pragma unroll
            for (int j = 0; j < 4; j++) {
                bf0[j] = *(const f16x8*)(P + boff[j] + c0);
                bf1[j] = *(const f16x8*)(P + boff[j] + c1);
            }
            if (t + 1 < nk) {           // finish tile t+1: A quads 2,3 (freed by (t-1).P3)
                GLD_A(buf ^ 1, 1, t + 1);
                GLD_A(buf ^ 1, 3, t + 1);
            }
            __builtin_amdgcn_s_barrier();
            __builtin_amdgcn_s_setprio(1);
#pragma unroll
            for (int j = 0; j < 4; j++) {
                acc[0][j] = __builtin_amdgcn_mfma_f32_16x16x32_f16(aA0, bf0[j], acc[0][j], 0, 0, 0);
                acc[0][j] = __builtin_amdgcn_mfma_f32_16x16x32_f16(aA1, bf1[j], acc[0][j], 0, 0, 0);
                acc[1][j] = __builtin_amdgcn_mfma_f32_16x16x32_f16(aB0, bf0[j], acc[1][j], 0, 0, 0);
                acc[1][j] = __builtin_amdgcn_mfma_f32_16x16x32_f16(aB1, bf1[j], acc[1][j], 0, 0, 0);
            }
            __builtin_amdgcn_s_setprio(0);
            __builtin_amdgcn_s_barrier();
        }

        // ---------------- phases 1..3: i=2q,2q+1 ----------------
#pragma unroll
        for (int q = 1; q < 4; q++) {
            f16x8 aA0 = *(const f16x8*)(P + aoff[2 * q] + c0);
            f16x8 aA1 = *(const f16x8*)(P + aoff[2 * q] + c1);
            f16x8 aB0 = *(const f16x8*)(P + aoff[2 * q + 1] + c0);
            f16x8 aB1 = *(const f16x8*)(P + aoff[2 * q + 1] + c1);
            if (t + 2 < nk) {
                if (q == 1) { GLD_B(buf, 0, t + 2); GLD_B(buf, 1, t + 2); }  // B freed at P0
                if (q == 2) { GLD_B(buf, 2, t + 2); GLD_B(buf, 3, t + 2); }
                if (q == 3) { GLD_A(buf, 0, t + 2); GLD_A(buf, 2, t + 2); }  // A quads 0,1 freed at P1
            }
            __builtin_amdgcn_s_barrier();
            __builtin_amdgcn_s_setprio(1);
#pragma unroll
            for (int j = 0; j < 4; j++) {
                acc[2 * q][j]     = __builtin_amdgcn_mfma_f32_16x16x32_f16(aA0, bf0[j], acc[2 * q][j], 0, 0, 0);
                acc[2 * q][j]     = __builtin_amdgcn_mfma_f32_16x16x32_f16(aA1, bf1[j], acc[2 * q][j], 0, 0, 0);
                acc[2 * q + 1][j] = __builtin_amdgcn_mfma_f32_16x16x32_f16(aB0, bf0[j], acc[2 * q + 1][j], 0, 0, 0);
                acc[2 * q + 1][j] = __builtin_amdgcn_mfma_f32_16x16x32_f16(aB1, bf1[j], acc[2 * q + 1][j], 0, 0, 0);
            }
            __builtin_amdgcn_s_setprio(0);
            __builtin_amdgcn_s_barrier();
        }
    }

    // ---- epilogue ----
    const int rq = l >> 4;
#pragma unroll
    for (int i = 0; i < 8; i++) {
#pragma unroll
        for (int j = 0; j < 4; j++) {
            int col = col0 + wc + j * 16 + (l & 15);
            float bs = bias[col];
#pragma unroll
            for (int r = 0; r < 4; r++) {
                int rowg = row0 + wr + i * 16 + rq * 4 + r;
                if (rowg >= M) continue;
                float vv = acc[i][j][r] + bs;
                size_t o = (size_t)rowg * N + col;
                if (EPI == 1) {
                    float gl = 0.5f * vv * (1.f + erff(vv * 0.70710678118654752f));
                    Ch[o] = f2h(gl);
                } else if (EPI == 2) {
                    Cf[o] = vv + resid[o];
                } else {
                    Cf[o] = vv;
                }
            }
        }
    }
}

// ============================================================================
// 1-term fp16 MFMA GEMM (proven config). 128x128, BK=32, double-buf 2-plane
// LDS (32KB, 4 blocks/CU), 16 MFMA/step, hoisted addressing.
// EPI: 1 = gelu(+bias) -> fp16 ; 2 = +bias+resid -> fp32
// ============================================================================
template<int EPI>
__global__ __launch_bounds__(256, 4) void gemm_1t(
    const u16* __restrict__ A, const u16* __restrict__ B,
    const float* __restrict__ bias, const float* __restrict__ resid,
    float* __restrict__ Cf, u16* __restrict__ Ch,
    int M, int N, int K)
{
    __shared__ u16 lds[2][2][4096];
    const int tid = threadIdx.x;
    const int l = tid & 63, w = tid >> 6;
    const int wr = (w >> 1) * 64, wc = (w & 1) * 64;
    int bx = blockIdx.x, by = blockIdx.y;
    xcd_swizzle(bx, by);
    const int row0 = by * 128, col0 = bx * 128;

    const int sg = w * 2;
    const int tl0 = sg * 16 + (l >> 2);
    const int tl1 = tl0 + 16;
    const int kq0 = (l & 3) ^ ((tl0 >> 1) & 3);
    const int kq1 = (l & 3) ^ ((tl1 >> 1) & 3);
    int ga0 = row0 + tl0; if (ga0 > M - 1) ga0 = M - 1;
    int ga1 = row0 + tl1; if (ga1 > M - 1) ga1 = M - 1;
    int gb0 = col0 + tl0; if (gb0 > N - 1) gb0 = N - 1;
    int gb1 = col0 + tl1; if (gb1 > N - 1) gb1 = N - 1;
    const u16* pA0 = A + (size_t)ga0 * K + kq0 * 8;
    const u16* pA1 = A + (size_t)ga1 * K + kq1 * 8;
    const u16* pB0 = B + (size_t)gb0 * K + kq0 * 8;
    const u16* pB1 = B + (size_t)gb1 * K + kq1 * 8;

    int offA[4], offB[4];
#pragma unroll
    for (int i = 0; i < 4; i++) {
        int ra = wr + i * 16 + (l & 15);
        offA[i] = ra * 32 + (((l >> 4) ^ ((ra >> 1) & 3)) << 3);
        int rb = wc + i * 16 + (l & 15);
        offB[i] = rb * 32 + (((l >> 4) ^ ((rb >> 1) & 3)) << 3);
    }

    f32x4 acc[4][4];
#pragma unroll
    for (int i = 0; i < 4; i++)
#pragma unroll
        for (int j = 0; j < 4; j++)
            acc[i][j] = (f32x4){0.f, 0.f, 0.f, 0.f};

    auto STAGE = [&](int buf, int kk) {
        gld_lds16(pA0 + kk, &lds[buf][0][(sg + 0) * 512]);
        gld_lds16(pA1 + kk, &lds[buf][0][(sg + 1) * 512]);
        gld_lds16(pB0 + kk, &lds[buf][1][(sg + 0) * 512]);
        gld_lds16(pB1 + kk, &lds[buf][1][(sg + 1) * 512]);
    };
    auto COMPUTE = [&](int buf) {
        f16x8 af[4], bf4[4];
#pragma unroll
        for (int i = 0; i < 4; i++) af[i] = *(const f16x8*)(&lds[buf][0][offA[i]]);
#pragma unroll
        for (int j = 0; j < 4; j++) bf4[j] = *(const f16x8*)(&lds[buf][1][offB[j]]);
#pragma unroll
        for (int i = 0; i < 4; i++)
#pragma unroll
            for (int j = 0; j < 4; j++)
                acc[i][j] = __builtin_amdgcn_mfma_f32_16x16x32_f16(af[i], bf4[j], acc[i][j], 0, 0, 0);
    };

    const int nk = K / 32;   // even for all our K
    STAGE(0, 0);
    __syncthreads();
    for (int t = 0; t < nk; t += 2) {
        if (t + 1 < nk) STAGE(1, (t + 1) * 32);
        COMPUTE(0);
        __syncthreads();
        if (t + 2 < nk) STAGE(0, (t + 2) * 32);
        COMPUTE(1);
        __syncthreads();
    }

    const int rq = l >> 4;
#pragma unroll
    for (int i = 0; i < 4; i++) {
#pragma unroll
        for (int j = 0; j < 4; j++) {
            int col = col0 + wc + j * 16 + (l & 15);
            float bs = bias[col];
#pragma unroll
            for (int r = 0; r < 4; r++) {
                int rowg = row0 + wr + i * 16 + rq * 4 + r;
                if (rowg >= M) continue;
                float vv = acc[i][j][r] + bs;
                size_t o = (size_t)rowg * N + col;
                if (EPI == 1) {
                    float gl = 0.5f * vv * (1.f + erff(vv * 0.70710678118654752f));
                    Ch[o] = f2h(gl);
                } else if (EPI == 2) {
                    Cf[o] = vv + resid[o];
                } else {
                    Cf[o] = vv;
                }
            }
        }
    }
}

// ============================================================================
// 256x128-tile fp16 GEMM, 512 threads / 8 waves, (512,4) cap (R25: validated,
// time-neutral vs 128x128, halves A-fetch). Fallback for MLP1 if dynamic-LDS
// attribute fails.
// ============================================================================
template<int EPI>
__global__ __launch_bounds__(512, 4) void gemm_256(
    const u16* __restrict__ A, const u16* __restrict__ B,
    const float* __restrict__ bias, const float* __restrict__ resid,
    float* __restrict__ Cf, u16* __restrict__ Ch,
    int M, int N, int K)
{
    __shared__ u16 ldsA[2][256 * 32];   // [dbuf][row*32 + k]
    __shared__ u16 ldsB[2][128 * 32];
    const int tid = threadIdx.x;
    const int l = tid & 63, w = tid >> 6;          // w = 0..7
    const int wr = (w >> 1) * 64, wc = (w & 1) * 64;  // 4x2 wave grid
    int bx = blockIdx.x, by = blockIdx.y;
    xcd_swizzle(bx, by);
    const int row0 = by * 256, col0 = bx * 128;

    const int sgA = w * 2;
    const int tlA0 = sgA * 16 + (l >> 2);
    const int tlA1 = tlA0 + 16;
    const int kqA0 = (l & 3) ^ ((tlA0 >> 1) & 3);
    const int kqA1 = (l & 3) ^ ((tlA1 >> 1) & 3);
    int gaA0 = row0 + tlA0; if (gaA0 > M - 1) gaA0 = M - 1;
    int gaA1 = row0 + tlA1; if (gaA1 > M - 1) gaA1 = M - 1;
    const u16* pA0 = A + (size_t)gaA0 * K + kqA0 * 8;
    const u16* pA1 = A + (size_t)gaA1 * K + kqA1 * 8;
    const int tlB = w * 16 + (l >> 2);
    const int kqB = (l & 3) ^ ((tlB >> 1) & 3);
    int gbB = col0 + tlB; if (gbB > N - 1) gbB = N - 1;
    const u16* pB = B + (size_t)gbB * K + kqB * 8;

    int offA[4], offB[4];
#pragma unroll
    for (int i = 0; i < 4; i++) {
        int ra = wr + i * 16 + (l & 15);
        offA[i] = ra * 32 + (((l >> 4) ^ ((ra >> 1) & 3)) << 3);
        int rb = wc + i * 16 + (l & 15);
        offB[i] = rb * 32 + (((l >> 4) ^ ((rb >> 1) & 3)) << 3);
    }

    f32x4 acc[4][4];
#pragma unroll
    for (int i = 0; i < 4; i++)
#pragma unroll
        for (int j = 0; j < 4; j++)
            acc[i][j] = (f32x4){0.f, 0.f, 0.f, 0.f};

    auto STAGE = [&](int buf, int kk) {
        gld_lds16(pA0 + kk, &ldsA[buf][(sgA + 0) * 512]);
        gld_lds16(pA1 + kk, &ldsA[buf][(sgA + 1) * 512]);
        gld_lds16(pB + kk, &ldsB[buf][w * 512]);
    };
    auto COMPUTE = [&](int buf) {
        f16x8 af[4], bf4[4];
#pragma unroll
        for (int i = 0; i < 4; i++) af[i] = *(const f16x8*)(&ldsA[buf][offA[i]]);
#pragma unroll
        for (int j = 0; j < 4; j++) bf4[j] = *(const f16x8*)(&ldsB[buf][offB[j]]);
#pragma unroll
        for (int i = 0; i < 4; i++)
#pragma unroll
            for (int j = 0; j < 4; j++)
                acc[i][j] = __builtin_amdgcn_mfma_f32_16x16x32_f16(af[i], bf4[j], acc[i][j], 0, 0, 0);
    };

    const int nk = K / 32;   // even
    STAGE(0, 0);
    __syncthreads();
    for (int t = 0; t < nk; t += 2) {
        if (t + 1 < nk) STAGE(1, (t + 1) * 32);
        COMPUTE(0);
        __syncthreads();
        if (t + 2 < nk) STAGE(0, (t + 2) * 32);
        COMPUTE(1);
        __syncthreads();
    }

    const int rq = l >> 4;
#pragma unroll
    for (int i = 0; i < 4; i++) {
#pragma unroll
        for (int j = 0; j < 4; j++) {
            int col = col0 + wc + j * 16 + (l & 15);
            float bs = bias[col];
#pragma unroll
            for (int r = 0; r < 4; r++) {
                int rowg = row0 + wr + i * 16 + rq * 4 + r;
                if (rowg >= M) continue;
                float vv = acc[i][j][r] + bs;
                size_t o = (size_t)rowg * N + col;
                if (EPI == 1) {
                    float gl = 0.5f * vv * (1.f + erff(vv * 0.70710678118654752f));
                    Ch[o] = f2h(gl);
                } else if (EPI == 2) {
                    Cf[o] = vv + resid[o];
                } else {
                    Cf[o] = vv;
                }
            }
        }
    }
}

// ============================================================================
// Fused QKV GEMM (fp16), proven structure.
// Epilogue: q (x0.125 -> qb), k -> kb, v -> transposed vtb.
// ============================================================================
__global__ __launch_bounds__(256, 4) void gemm_qkv(
    const u16* __restrict__ A, const u16* __restrict__ B,
    const float* __restrict__ bq, const float* __restrict__ bk,
    const float* __restrict__ bv,
    u16* __restrict__ qb, u16* __restrict__ kb, u16* __restrict__ vt,
    int M, int N, int K)
{
    __shared__ u16 lds[2][2][4096];
    const int tid = threadIdx.x;
    const int l = tid & 63, w = tid >> 6;
    const int wr = (w >> 1) * 64, wc = (w & 1) * 64;
    int bx = blockIdx.x, by = blockIdx.y;
    xcd_swizzle(bx, by);
    const int row0 = by * 128, col0 = bx * 128;

    const int sg = w * 2;
    const int tl0 = sg * 16 + (l >> 2);
    const int tl1 = tl0 + 16;
    const int kq0 = (l & 3) ^ ((tl0 >> 1) & 3);
    const int kq1 = (l & 3) ^ ((tl1 >> 1) & 3);
    int ga0 = row0 + tl0; if (ga0 > M - 1) ga0 = M - 1;
    int ga1 = row0 + tl1; if (ga1 > M - 1) ga1 = M - 1;
    int gb0 = col0 + tl0; if (gb0 > N - 1) gb0 = N - 1;
    int gb1 = col0 + tl1; if (gb1 > N - 1) gb1 = N - 1;
    const u16* pA0 = A + (size_t)ga0 * K + kq0 * 8;
    const u16* pA1 = A + (size_t)ga1 * K + kq1 * 8;
    const u16* pB0 = B + (size_t)gb0 * K + kq0 * 8;
    const u16* pB1 = B + (size_t)gb1 * K + kq1 * 8;

    int offA[4], offB[4];
#pragma unroll
    for (int i = 0; i < 4; i++) {
        int ra = wr + i * 16 + (l & 15);
        offA[i] = ra * 32 + (((l >> 4) ^ ((ra >> 1) & 3)) << 3);
        int rb = wc + i * 16 + (l & 15);
        offB[i] = rb * 32 + (((l >> 4) ^ ((rb >> 1) & 3)) << 3);
    }

    f32x4 acc[4][4];
#pragma unroll
    for (int i = 0; i < 4; i++)
#pragma unroll
        for (int j = 0; j < 4; j++)
            acc[i][j] = (f32x4){0.f, 0.f, 0.f, 0.f};

    auto STAGE = [&](int buf, int kk) {
        gld_lds16(pA0 + kk, &lds[buf][0][(sg + 0) * 512]);
        gld_lds16(pA1 + kk, &lds[buf][0][(sg + 1) * 512]);
        gld_lds16(pB0 + kk, &lds[buf][1][(sg + 0) * 512]);
        gld_lds16(pB1 + kk, &lds[buf][1][(sg + 1) * 512]);
    };
    auto COMPUTE = [&](int buf) {
        f16x8 af[4], bf4[4];
#pragma unroll
        for (int i = 0; i < 4; i++) af[i] = *(const f16x8*)(&lds[buf][0][offA[i]]);
#pragma unroll
        for (int j = 0; j < 4; j++) bf4[j] = *(const f16x8*)(&lds[buf][1][offB[j]]);
#pragma unroll
        for (int i = 0; i < 4; i++)
#pragma unroll
            for (int j = 0; j < 4; j++)
                acc[i][j] = __builtin_amdgcn_mfma_f32_16x16x32_f16(af[i], bf4[j], acc[i][j], 0, 0, 0);
    };

    const int nk = K / 32;
    STAGE(0, 0);
    __syncthreads();
    for (int t = 0; t < nk; t += 2) {
        if (t + 1 < nk) STAGE(1, (t + 1) * 32);
        COMPUTE(0);
        __syncthreads();
        if (t + 2 < nk) STAGE(0, (t + 2) * 32);
        COMPUTE(1);
        __syncthreads();
    }

    const int rq = l >> 4;
#pragma unroll
    for (int i = 0; i < 4; i++) {
#pragma unroll
        for (int j = 0; j < 4; j++) {
            int col = col0 + wc + j * 16 + (l & 15);
#pragma unroll
            for (int r = 0; r < 4; r++) {
                int rowg = row0 + wr + i * 16 + rq * 4 + r;
                if (rowg >= M) continue;
                float a = acc[i][j][r];
                if (col < 1024) {
                    qb[(size_t)rowg * 1024 + col] = f2h((a + bq[col]) * 0.125f);
                } else if (col < 2048) {
                    int c2 = col - 1024;
                    kb[(size_t)rowg * 1024 + c2] = f2h(a + bk[c2]);
                } else {
                    int c2 = col - 2048;
                    u32 rg = (u32)rowg;
                    u32 bb = rg / 577u;
                    u32 key = rg - bb * 577u;
                    vt[((size_t)((bb * 16 + (c2 >> 6)) * 64 + (c2 & 63))) * 640 + key] =
                        f2h(a + bv[c2]);
                }
            }
        }
    }
}

// ============================================================================
// MFMA flash attention (fp16 operands, fp32 accum). Output: fp16 ctx.
// K/V LDS tiles XOR-swizzled; R27 T14 reg-staged prefetch (kept, neutral).
// ============================================================================
__global__ __launch_bounds__(256) void flash_mfma(const u16* __restrict__ Qg,
                                                  const u16* __restrict__ Kg,
                                                  const u16* __restrict__ Vt,
                                                  u16* __restrict__ Oh) {
    __shared__ u16 Kl[64 * 64];     // [key][dh], 16B slots swizzled
    __shared__ u16 Vl[64 * 64];     // [d][key], 16B slots swizzled
    __shared__ u16 Pl[64][72];      // wave-private 16-row stripes, padded

    int bx = blockIdx.x, by = blockIdx.y;
    xcd_swizzle(bx, by);
    const int qt = bx, bh = by;
    const int b = bh >> 4, h = bh & 15;
    const int tid = threadIdx.x;
    const int l = tid & 63, w = tid >> 6;
    const int q0 = qt * 64;

    int qrow = q0 + w * 16 + (l & 15); if (qrow > 576) qrow = 576;
    const u16* qp = Qg + ((size_t)(b * 577 + qrow)) * 1024 + h * 64 + (l >> 4) * 8;
    f16x8 qf0 = *(const f16x8*)qp;
    f16x8 qf1 = *(const f16x8*)(qp + 32);

    const int swk = ((l & 7) ^ (l >> 3)) * 8;

    f32x4 ctx[4];
#pragma unroll
    for (int d = 0; d < 4; d++) ctx[d] = (f32x4){0.f, 0.f, 0.f, 0.f};
    float m_r[4], l_r[4];
#pragma unroll
    for (int r = 0; r < 4; r++) { m_r[r] = -1e30f; l_r[r] = 0.f; }

    // prologue: stage tile 0 via global_load_lds
#pragma unroll
    for (int c2 = 0; c2 < 2; ++c2) {
        int c = w * 2 + c2;
        int key = c * 8 + (l >> 3); if (key > 576) key = 576;
        const u16* ksrc = Kg + ((size_t)(b * 577 + key)) * 1024 + h * 64 + swk;
        gld_lds16(ksrc, Kl + c * 512);
        int d = c * 8 + (l >> 3);
        const u16* vsrc = Vt + ((size_t)(bh * 64 + d)) * 640 + swk;
        gld_lds16(vsrc, Vl + c * 512);
    }
    __syncthreads();

    for (int kt = 0; kt < 10; ++kt) {
        f16x8 kreg[2], vreg[2];
        if (kt < 9) {
            const int kb2 = (kt + 1) * 64;
#pragma unroll
            for (int c2 = 0; c2 < 2; ++c2) {
                int c = w * 2 + c2;
                int key = kb2 + c * 8 + (l >> 3); if (key > 576) key = 576;
                kreg[c2] = *(const f16x8*)(Kg + ((size_t)(b * 577 + key)) * 1024 + h * 64 + swk);
                int d = c * 8 + (l >> 3);
                vreg[c2] = *(const f16x8*)(Vt + ((size_t)(bh * 64 + d)) * 640 + kb2 + swk);
            }
        }

        const int kb = kt * 64;
        f32x4 sc[4];
#pragma unroll
        for (int sub = 0; sub < 4; ++sub) {
            sc[sub] = (f32x4){0.f, 0.f, 0.f, 0.f};
            int rr = sub * 16 + (l & 15);
            int c0 = (l >> 4) ^ (rr & 7);
            int c1 = ((l >> 4) + 4) ^ (rr & 7);
            f16x8 kf0 = *(const f16x8*)(Kl + rr * 64 + c0 * 8);
            f16x8 kf1 = *(const f16x8*)(Kl + rr * 64 + c1 * 8);
            sc[sub] = __builtin_amdgcn_mfma_f32_16x16x32_f16(qf0, kf0, sc[sub], 0, 0, 0);
            sc[sub] = __builtin_amdgcn_mfma_f32_16x16x32_f16(qf1, kf1, sc[sub], 0, 0, 0);
        }

        bool valid[4];
#pragma unroll
        for (int sub = 0; sub < 4; ++sub) valid[sub] = (kb + sub * 16 + (l & 15)) < Sn;

#pragma unroll
        for (int r = 0; r < 4; ++r) {
            float s0 = valid[0] ? sc[0][r] : -1e30f;
            float s1 = valid[1] ? sc[1][r] : -1e30f;
            float s2 = valid[2] ? sc[2][r] : -1e30f;
            float s3 = valid[3] ? sc[3][r] : -1e30f;
            float mx = fmaxf(fmaxf(s0, s1), fmaxf(s2, s3));
            mx = fmaxf(mx, __shfl_xor(mx, 1));
            mx = fmaxf(mx, __shfl_xor(mx, 2));
            mx = fmaxf(mx, __shfl_xor(mx, 4));
            mx = fmaxf(mx, __shfl_xor(mx, 8));
            float mnew = fmaxf(m_r[r], mx);
            float scale = __expf(m_r[r] - mnew);
            float p0 = valid[0] ? __expf(s0 - mnew) : 0.f;
            float p1 = valid[1] ? __expf(s1 - mnew) : 0.f;
            float p2 = valid[2] ? __expf(s2 - mnew) : 0.f;
            float p3 = valid[3] ? __expf(s3 - mnew) : 0.f;
            int prow = w * 16 + (l >> 4) * 4 + r;
            int pcol = l & 15;
            Pl[prow][pcol]      = f2h(p0);
            Pl[prow][pcol + 16] = f2h(p1);
            Pl[prow][pcol + 32] = f2h(p2);
            Pl[prow][pcol + 48] = f2h(p3);
            float rsum = p0 + p1 + p2 + p3;
            rsum += __shfl_xor(rsum, 1);
            rsum += __shfl_xor(rsum, 2);
            rsum += __shfl_xor(rsum, 4);
            rsum += __shfl_xor(rsum, 8);
            l_r[r] = l_r[r] * scale + rsum;
            m_r[r] = mnew;
#pragma unroll
            for (int d = 0; d < 4; ++d) ctx[d][r] *= scale;
        }

#pragma unroll
        for (int ks = 0; ks < 2; ++ks) {
            f16x8 pf = *(const f16x8*)(&Pl[w * 16 + (l & 15)][ks * 32 + (l >> 4) * 8]);
#pragma unroll
            for (int d = 0; d < 4; ++d) {
                int rr = d * 16 + (l & 15);
                int cv = (ks * 4 + (l >> 4)) ^ (rr & 7);
                f16x8 vf = *(const f16x8*)(Vl + rr * 64 + cv * 8);
                ctx[d] = __builtin_amdgcn_mfma_f32_16x16x32_f16(pf, vf, ctx[d], 0, 0, 0);
            }
        }
        __syncthreads();

        if (kt < 9) {
#pragma unroll
            for (int c2 = 0; c2 < 2; ++c2) {
                int c = w * 2 + c2;
                *(f16x8*)(Kl + c * 512 + l * 8) = kreg[c2];
                *(f16x8*)(Vl + c * 512 + l * 8) = vreg[c2];
            }
            __syncthreads();
        }
    }

#pragma unroll
    for (int r = 0; r < 4; ++r) {
        int q = q0 + w * 16 + (l >> 4) * 4 + r;
        if (q >= Sn) continue;
        float inv = 1.f / l_r[r];
#pragma unroll
        for (int d = 0; d < 4; ++d) {
            float t = ctx[d][r] * inv;
            size_t o = ((size_t)(b * 577 + q)) * 1024 + h * 64 + d * 16 + (l & 15);
            Oh[o] = f2h(t);
        }
    }
}

// ============================================================================
// fp32 tiled GEMM (fallback path only)
// ============================================================================
template<int EPI>
__global__ __launch_bounds__(256) void gemm_kernel(const float* __restrict__ A,
                                                   const float* __restrict__ W,
                                                   const float* __restrict__ bias,
                                                   const float* __restrict__ resid,
                                                   float* __restrict__ C,
                                                   int M, int N, int K) {
    const int BM = 64, BN = 64, BK = 16;
    __shared__ float As[BK][BM + 1];
    __shared__ float Ws[BK][BN];
    int tx = threadIdx.x, ty = threadIdx.y;
    int tid = ty * 16 + tx;
    int row0 = blockIdx.y * BM, col0 = blockIdx.x * BN;
    float acc[4][4] = {};
    for (int k0 = 0; k0 < K; k0 += BK) {
#pragma unroll
        for (int i = 0; i < 4; i++) {
            int idx = i * 256 + tid;
            int ar = idx >> 4, ac = idx & 15;
            int grow = row0 + ar;
            As[ac][ar] = (grow < M) ? A[(size_t)grow * K + k0 + ac] : 0.f;
        }
#pragma unroll
        for (int i = 0; i < 4; i++) {
            int idx = i * 256 + tid;
            int wr = idx >> 6, wcc = idx & 63;
            Ws[wr][wcc] = W[(size_t)(k0 + wr) * N + col0 + wcc];
        }
        __syncthreads();
#pragma unroll
        for (int kk = 0; kk < BK; kk++) {
            float a[4], wv[4];
#pragma unroll
            for (int i = 0; i < 4; i++) a[i] = As[kk][ty * 4 + i];
#pragma unroll
            for (int j = 0; j < 4; j++) wv[j] = Ws[kk][tx * 4 + j];
#pragma unroll
            for (int i = 0; i < 4; i++)
#pragma unroll
                for (int j = 0; j < 4; j++)
                    acc[i][j] += a[i] * wv[j];
        }
        __syncthreads();
    }
#pragma unroll
    for (int i = 0; i < 4; i++) {
        int grow = row0 + ty * 4 + i;
        if (grow >= M) continue;
#pragma unroll
        for (int j = 0; j < 4; j++) {
            int gcol = col0 + tx * 4 + j;
            float r = acc[i][j] + bias[gcol];
            if (EPI == 1) r = 0.5f * r * (1.f + erff(r * 0.70710678118654752f));
            if (EPI == 2) r += resid[(size_t)grow * N + gcol];
            C[(size_t)grow * N + gcol] = r;
        }
    }
}

// ============================================================================
// fp32 flash attention (fallback path only)
// ============================================================================
__global__ __launch_bounds__(256) void flash_kernel(const float* __restrict__ Q,
                                                    const float* __restrict__ K,
                                                    const float* __restrict__ V,
                                                    float* __restrict__ Of) {
    __shared__ float Qs[64][68];
    __shared__ float KT[64][68];
    __shared__ float Vs[64][68];
    __shared__ float Ps[64][68];

    int qt = blockIdx.x;
    int bh = blockIdx.y;
    int b = bh >> 4, h = bh & 15;
    int tid = threadIdx.x;
    int tx = tid & 15, ty = tid >> 4;
    size_t base = ((size_t)b * Sn) * Dn + (size_t)h * DHn;
    int q0 = qt * 64;

    {
        int r = tid >> 4;
        int c = (tid & 15) * 4;
#pragma unroll
        for (int i = 0; i < 4; i++) {
            int rr = r + i * 16;
            int gq = q0 + rr;
            float4 val = make_float4(0.f, 0.f, 0.f, 0.f);
            if (gq < Sn) val = *(const float4*)&Q[base + (size_t)gq * Dn + c];
            Qs[rr][c + 0] = val.x * 0.125f;
            Qs[rr][c + 1] = val.y * 0.125f;
            Qs[rr][c + 2] = val.z * 0.125f;
            Qs[rr][c + 3] = val.w * 0.125f;
        }
    }

    float m_r[4], l_r[4], acc[4][4];
#pragma unroll
    for (int i = 0; i < 4; i++) {
        m_r[i] = -1e30f; l_r[i] = 0.f;
#pragma unroll
        for (int j = 0; j < 4; j++) acc[i][j] = 0.f;
    }

    for (int kt = 0; kt < 10; kt++) {
        int kb = kt * 64;
        {
            int r = tid >> 4;
            int c = (tid & 15) * 4;
#pragma unroll
            for (int i = 0; i < 4; i++) {
                int rr = r + i * 16;
                int gk = kb + rr;
                float4 kv = make_float4(0.f, 0.f, 0.f, 0.f);
                float4 vv = make_float4(0.f, 0.f, 0.f, 0.f);
                if (gk < Sn) {
                    kv = *(const float4*)&K[base + (size_t)gk * Dn + c];
                    vv = *(const float4*)&V[base + (size_t)gk * Dn + c];
                }
                KT[c + 0][rr] = kv.x;
                KT[c + 1][rr] = kv.y;
                KT[c + 2][rr] = kv.z;
                KT[c + 3][rr] = kv.w;
                Vs[rr][c + 0] = vv.x;
                Vs[rr][c + 1] = vv.y;
                Vs[rr][c + 2] = vv.z;
                Vs[rr][c + 3] = vv.w;
            }
        }
        __syncthreads();

        float s[4][4] = {};
#pragma unroll
        for (int kk4 = 0; kk4 < 16; kk4++) {
            float4 a4[4], b4[4];
#pragma unroll
            for (int i = 0; i < 4; i++) a4[i] = *(const float4*)&Qs[ty * 4 + i][kk4 * 4];
#pragma unroll
            for (int q = 0; q < 4; q++) b4[q] = *(const float4*)&KT[kk4 * 4 + q][tx * 4];
#pragma unroll
            for (int i = 0; i < 4; i++) {
                float av[4] = {a4[i].x, a4[i].y, a4[i].z, a4[i].w};
#pragma unroll
                for (int q = 0; q < 4; q++) {
                    s[i][0] += av[q] * b4[q].x;
                    s[i][1] += av[q] * b4[q].y;
                    s[i][2] += av[q] * b4[q].z;
                    s[i][3] += av[q] * b4[q].w;
                }
            }
        }

        bool cvalid[4];
#pragma unroll
        for (int j = 0; j < 4; j++) cvalid[j] = (kb + tx * 4 + j) < Sn;
#pragma unroll
        for (int i = 0; i < 4; i++) {
            float lmax = -1e30f;
#pragma unroll
            for (int j = 0; j < 4; j++) if (cvalid[j]) lmax = fmaxf(lmax, s[i][j]);
            lmax = fmaxf(lmax, __shfl_xor(lmax, 1));
            lmax = fmaxf(lmax, __shfl_xor(lmax, 2));
            lmax = fmaxf(lmax, __shfl_xor(lmax, 4));
            lmax = fmaxf(lmax, __shfl_xor(lmax, 8));
            float mnew = fmaxf(m_r[i], lmax);
            float scale = __expf(m_r[i] - mnew);
            float rsum = 0.f;
#pragma unroll
            for (int j = 0; j < 4; j++) {
                float p = cvalid[j] ? __expf(s[i][j] - mnew) : 0.f;
                s[i][j] = p;
                rsum += p;
            }
            rsum += __shfl_xor(rsum, 1);
            rsum += __shfl_xor(rsum, 2);
            rsum += __shfl_xor(rsum, 4);
            rsum += __shfl_xor(rsum, 8);
            l_r[i] = l_r[i] * scale + rsum;
            m_r[i] = mnew;
#pragma unroll
            for (int j = 0; j < 4; j++) acc[i][j] *= scale;
        }

#pragma unroll
        for (int i = 0; i < 4; i++)
#pragma unroll
            for (int j = 0; j < 4; j++)
                Ps[ty * 4 + i][tx * 4 + j] = s[i][j];
        __syncthreads();

#pragma unroll
        for (int kk4 = 0; kk4 < 16; kk4++) {
            float4 a4[4], b4[4];
#pragma unroll
            for (int i = 0; i < 4; i++) a4[i] = *(const float4*)&Ps[ty * 4 + i][kk4 * 4];
#pragma unroll
            for (int q = 0; q < 4; q++) b4[q] = *(const float4*)&Vs[kk4 * 4 + q][tx * 4];
#pragma unroll
            for (int i = 0; i < 4; i++) {
                float av[4] = {a4[i].x, a4[i].y, a4[i].z, a4[i].w};
#pragma unroll
                for (int q = 0; q < 4; q++) {
                    acc[i][0] += av[q] * b4[q].x;
                    acc[i][1] += av[q] * b4[q].y;
                    acc[i][2] += av[q] * b4[q].z;
                    acc[i][3] += av[q] * b4[q].w;
                }
            }
        }
        __syncthreads();
    }

#pragma unroll
    for (int i = 0; i < 4; i++) {
        int gq = q0 + ty * 4 + i;
        if (gq >= Sn) continue;
        float inv = 1.f / l_r[i];
#pragma unroll
        for (int j = 0; j < 4; j++)
            Of[base + (size_t)gq * Dn + tx * 4 + j] = acc[i][j] * inv;
    }
}

// ============================================================================
extern "C" void kernel_launch(void* const* d_in, const int* in_sizes, int n_in,
                              void* d_out, int out_size, void* d_ws, size_t ws_size,
                              hipStream_t stream) {
    const float* x    = (const float*)d_in[0];
    const float* ln1g = (const float*)d_in[1];
    const float* ln1b = (const float*)d_in[2];
    const float* wq   = (const float*)d_in[3];
    const float* bq   = (const float*)d_in[4];
    const float* wk   = (const float*)d_in[5];
    const float* bk   = (const float*)d_in[6];
    const float* wv   = (const float*)d_in[7];
    const float* bv   = (const float*)d_in[8];
    const float* wo   = (const float*)d_in[9];
    const float* bo   = (const float*)d_in[10];
    const float* ln2g = (const float*)d_in[11];
    const float* ln2b = (const float*)d_in[12];
    const float* w1   = (const float*)d_in[13];
    const float* b1   = (const float*)d_in[14];
    const float* w2   = (const float*)d_in[15];
    const float* b2   = (const float*)d_in[16];
    float* out = (float*)d_out;
    char* ws = (char*)d_ws;

    const size_t WHALF_D = (size_t)1024 * 1024 * 2;   // 2 MB
    const size_t WHALF_F = (size_t)4096 * 1024 * 2;   // 8 MB
    const size_t HALF_XN = (size_t)NROW * 1024 * 2;   // 18,907,136
    const size_t BASE_A  = 8 * WHALF_D + 4 * WHALF_F; // 50,331,648 (weights)
    const size_t NEED = BASE_A + 10 * HALF_XN;        // 239,403,008

    if (ws_size >= NEED) {
        // -------- fp16 MFMA path --------
        u16* wqkvT = (u16*)(ws);                          // [0, 6MB) fused q|k|v
        u16* woT   = (u16*)(ws + 6 * WHALF_D);            // 2 MB
        u16* w1T   = (u16*)(ws + 8 * WHALF_D);            // 8 MB
        u16* w2T   = (u16*)(ws + 8 * WHALF_D + 2 * WHALF_F);
        char* S = ws + BASE_A;
        u16* xn_h  = (u16*)(S + 0 * HALF_XN);
        u16* qb    = (u16*)(S + 2 * HALF_XN);
        u16* kb2   = (u16*)(S + 3 * HALF_XN);
        u16* vtb   = (u16*)(S + 4 * HALF_XN);
        u16* ctx_h = (u16*)(S + 8 * HALF_XN);
        u16* xn2_h = (u16*)(S + 9 * HALF_XN);
        u16* hm_h  = (u16*)(S + 0 * HALF_XN);   // spans S0-3

        // R26: weight conversions + vtb zeroing + LN1 in ONE dispatch
        prep_all<<<22800, 256, 0, stream>>>(wq, wk, wv, wo, w1, w2,
                                            x, ln1g, ln1b,
                                            wqkvT, woT, w1T, w2T, vtb, xn_h);

        gemm_qkv<<<dim3(24, 73), 256, 0, stream>>>(xn_h, wqkvT, bq, bk, bv,
                                                   qb, kb2, vtb, NROW, 3072, 1024);
        flash_mfma<<<dim3(10, Bn * Hn), 256, 0, stream>>>(qb, kb2, vtb, ctx_h);
        // proj: +bias+resid -> fp32 out
        gemm_1t<2><<<dim3(8, 73), 256, 0, stream>>>(
            ctx_h, woT, bo, x, out, nullptr, NROW, 1024, 1024);
        ln_f16<<<NROW, 256, 0, stream>>>(out, ln2g, ln2b, xn2_h);

        // MLP1: gelu -> fp16 hm.  R28: 8-phase 256x256 (128KB dynamic LDS),
        // guarded by the dynamic-LDS attribute; fallback = proven gemm_256.
        bool use8p = (hipFuncSetAttribute(
                          reinterpret_cast<const void*>(&gemm_8p<1>),
                          hipFuncAttributeMaxDynamicSharedMemorySize,
                          131072) == hipSuccess);
        if (use8p) {
            gemm_8p<1><<<dim3(16, 37), 512, 131072, stream>>>(
                xn2_h, w1T, b1, nullptr, nullptr, hm_h, NROW, 4096, 1024);
        } else {
            gemm_256<1><<<dim3(32, 37), 512, 0, stream>>>(
                xn2_h, w1T, b1, nullptr, nullptr, hm_h, NROW, 4096, 1024);
        }
        // MLP2: +bias+resid -> fp32 out (proven 128x128)
        gemm_1t<2><<<dim3(8, 73), 256, 0, stream>>>(
            hm_h, w2T, b2, out, out, nullptr, NROW, 1024, 4096);
    } else {
        // -------- fp32 fallback path (proven) --------
        const size_t SZ = (size_t)NROW * Dn * sizeof(float);
        float* qbuf  = (float*)(ws);
        float* kbuf  = (float*)(ws + SZ);
        float* vbuf  = (float*)(ws + 2 * SZ);
        float* hmid  = (float*)(ws);
        float* xnbuf = (float*)(ws + 4 * SZ);
        float* ctx   = (float*)(ws + 5 * SZ);
        float* x1    = (float*)(ws + 6 * SZ);
        dim3 blk2(16, 16);
        dim3 gD(Dn / 64, (NROW + 63) / 64);
        dim3 gF(Fn / 64, (NROW + 63) / 64);
        ln_kernel<<<NROW, 256, 0, stream>>>(x, ln1g, ln1b, xnbuf);
        gemm_kernel<0><<<gD, blk2, 0, stream>>>(xnbuf, wq, bq, nullptr, qbuf, NROW, Dn, Dn);
        gemm_kernel<0><<<gD, blk2, 0, stream>>>(xnbuf, wk, bk, nullptr, kbuf, NROW, Dn, Dn);
        gemm_kernel<0><<<gD, blk2, 0, stream>>>(xnbuf, wv, bv, nullptr, vbuf, NROW, Dn, Dn);
        flash_kernel<<<dim3(10, Bn * Hn), 256, 0, stream>>>(qbuf, kbuf, vbuf, ctx);
        gemm_kernel<2><<<gD, blk2, 0, stream>>>(ctx, wo, bo, x, x1, NROW, Dn, Dn);
        ln_kernel<<<NROW, 256, 0, stream>>>(x1, ln2g, ln2b, xnbuf);
        gemm_kernel<1><<<gF, blk2, 0, stream>>>(xnbuf, w1, b1, nullptr, hmid, NROW, Fn, Dn);
        gemm_kernel<2><<<gD, blk2, 0, stream>>>(hmid, w2, b2, x1, out, NROW, Dn, Fn);
    }
}

// Round 29
// 549.260 us; speedup vs baseline: 1.1251x; 1.1251x over previous
//
#include <hip/hip_runtime.h>
#include <hip/hip_fp16.h>
#include <math.h>

#define Bn 16
#define Sn 577
#define Dn 1024
#define Hn 16
#define DHn 64
#define Fn 4096
#define NROW (Bn*Sn)   // 9232
#define EPSf 1e-6f

typedef unsigned short u16;
typedef unsigned int u32;
typedef __attribute__((ext_vector_type(8))) _Float16 f16x8;
typedef __attribute__((ext_vector_type(4))) float f32x4;

__device__ inline u16 f2h(float x) { return __half_as_ushort(__float2half(x)); }

// XCD-aware bijective block swizzle (MI355X: 8 XCDs, round-robin dispatch).
__device__ inline void xcd_swizzle(int& bx, int& by) {
    int gx = gridDim.x;
    int nwg = gx * gridDim.y;
    int n = by * gx + bx;
    if ((nwg & 7) == 0) {
        int cpx = nwg >> 3;
        int w = (n & 7) * cpx + (n >> 3);
        bx = w % gx;
        by = w / gx;
    }
}

// ============================================================================
// Fused prologue (R26): weight convert + vtb zeroing + LN1 in ONE dispatch.
//   [0,4096)        wq/wk/wv/wo -> wqkvT/woT   (32x32 LDS-transpose tiles)
//   [4096,8192)     w1 -> w1T   (grid 128x32)
//   [8192,12288)    w2 -> w2T   (grid 32x128)
//   [12288,13568)   zero vtb    (1280 blocks x 16KB = 20,971,520 B exact)
//   [13568,22800)   LN1 row (t-13568) : x -> xn_h (fp16)
// ============================================================================
__device__ inline void conv_tile(const float* __restrict__ W, u16* __restrict__ T16,
                                 int K, int N, int bx, int by) {
    __shared__ float t[32][33];
    int n0 = bx * 32, k0 = by * 32;
    int tx = threadIdx.x & 31, ty = threadIdx.x >> 5;
#pragma unroll
    for (int i = 0; i < 4; i++) {
        int kk = ty * 4 + i;
        t[kk][tx] = W[(size_t)(k0 + kk) * N + n0 + tx];
    }
    __syncthreads();
#pragma unroll
    for (int i = 0; i < 4; i++) {
        int nn = ty * 4 + i;
        T16[(size_t)(n0 + nn) * K + k0 + tx] = f2h(t[tx][nn]);
    }
}

__device__ inline void ln_row_f16(const float* __restrict__ x,
                                  const float* __restrict__ g,
                                  const float* __restrict__ b,
                                  u16* __restrict__ oh, int row) {
    int tid = threadIdx.x;
    const float* xr = x + (size_t)row * Dn;
    float v[4];
    float s = 0.f;
#pragma unroll
    for (int i = 0; i < 4; i++) { v[i] = xr[tid + i * 256]; s += v[i]; }
    __shared__ float red[256];
    red[tid] = s; __syncthreads();
    for (int o = 128; o > 0; o >>= 1) { if (tid < o) red[tid] += red[tid + o]; __syncthreads(); }
    float mean = red[0] * (1.f / Dn);
    __syncthreads();
    float sq = 0.f;
#pragma unroll
    for (int i = 0; i < 4; i++) { float d = v[i] - mean; sq += d * d; }
    red[tid] = sq; __syncthreads();
    for (int o = 128; o > 0; o >>= 1) { if (tid < o) red[tid] += red[tid + o]; __syncthreads(); }
    float rstd = rsqrtf(red[0] * (1.f / Dn) + EPSf);
#pragma unroll
    for (int i = 0; i < 4; i++) {
        int c = tid + i * 256;
        float y = (v[i] - mean) * rstd * g[c] + b[c];
        oh[(size_t)row * Dn + c] = f2h(y);
    }
}

__global__ __launch_bounds__(256) void prep_all(
    const float* __restrict__ wq, const float* __restrict__ wk,
    const float* __restrict__ wv, const float* __restrict__ wo,
    const float* __restrict__ w1, const float* __restrict__ w2,
    const float* __restrict__ x, const float* __restrict__ ln1g,
    const float* __restrict__ ln1b,
    u16* __restrict__ wqkvT, u16* __restrict__ woT,
    u16* __restrict__ w1T, u16* __restrict__ w2T,
    u16* __restrict__ vtb, u16* __restrict__ xn_h)
{
    int t = blockIdx.x;
    if (t < 4096) {
        int which = t >> 10;          // 0=wq 1=wk 2=wv 3=wo
        int t2 = t & 1023;
        int bx = t2 & 31, by = t2 >> 5;
        const float* src = (which == 0) ? wq : (which == 1) ? wk : (which == 2) ? wv : wo;
        u16* dst = (which == 3) ? woT : (wqkvT + (size_t)which * 1024 * 1024);
        conv_tile(src, dst, 1024, 1024, bx, by);
    } else if (t < 8192) {
        int t2 = t - 4096;
        conv_tile(w1, w1T, 1024, 4096, t2 & 127, t2 >> 7);
    } else if (t < 12288) {
        int t2 = t - 8192;
        conv_tile(w2, w2T, 4096, 1024, t2 & 31, t2 >> 5);
    } else if (t < 13568) {
        // zero V^T padding buffer: 1280 blocks x 16384 B
        size_t base = (size_t)(t - 12288) * 16384 + (size_t)threadIdx.x * 16;
        char* p = (char*)vtb + base;
        float4 z = make_float4(0.f, 0.f, 0.f, 0.f);
#pragma unroll
        for (int i = 0; i < 4; i++) *(float4*)(p + (size_t)i * 4096) = z;
    } else {
        ln_row_f16(x, ln1g, ln1b, xn_h, t - 13568);
    }
}

// ============================================================================
// LayerNorm -> fp16 (standalone, used for LN2)
// ============================================================================
__global__ __launch_bounds__(256) void ln_f16(const float* __restrict__ x,
                                              const float* __restrict__ g,
                                              const float* __restrict__ b,
                                              u16* __restrict__ oh) {
    ln_row_f16(x, g, b, oh, blockIdx.x);
}

// fp32-output LN (fallback path)
__global__ __launch_bounds__(256) void ln_kernel(const float* __restrict__ x,
                                                 const float* __restrict__ g,
                                                 const float* __restrict__ b,
                                                 float* __restrict__ out) {
    int row = blockIdx.x;
    int tid = threadIdx.x;
    const float* xr = x + (size_t)row * Dn;
    float v[4];
    float s = 0.f;
#pragma unroll
    for (int i = 0; i < 4; i++) { v[i] = xr[tid + i * 256]; s += v[i]; }
    __shared__ float red[256];
    red[tid] = s; __syncthreads();
    for (int o = 128; o > 0; o >>= 1) { if (tid < o) red[tid] += red[tid + o]; __syncthreads(); }
    float mean = red[0] * (1.f / Dn);
    __syncthreads();
    float sq = 0.f;
#pragma unroll
    for (int i = 0; i < 4; i++) { float d = v[i] - mean; sq += d * d; }
    red[tid] = sq; __syncthreads();
    for (int o = 128; o > 0; o >>= 1) { if (tid < o) red[tid] += red[tid + o]; __syncthreads(); }
    float rstd = rsqrtf(red[0] * (1.f / Dn) + EPSf);
    float* orow = out + (size_t)row * Dn;
#pragma unroll
    for (int i = 0; i < 4; i++) {
        int c = tid + i * 256;
        orow[c] = (v[i] - mean) * rstd * g[c] + b[c];
    }
}

// ============================================================================
// Shared GEMM staging helpers
// ============================================================================
__device__ inline void gld_lds16(const u16* g, u16* l) {
    __builtin_amdgcn_global_load_lds((const __attribute__((address_space(1))) void*)g,
                                     (__attribute__((address_space(3))) void*)l,
                                     16, 0, 0);
}

// ============================================================================
// 1-term fp16 MFMA GEMM (proven config). 128x128, BK=32, double-buf 2-plane
// LDS (32KB, 4 blocks/CU), 16 MFMA/step, hoisted addressing.
// Probed neighborhood (all worse): (256,5) spills acc (R15); ring-4 counted
// vmcnt 64KB (R18 -13%); BK=64 64KB (R20 -11%); 64x128 tile (R9 -4x);
// 256x128 @(512,6) spills (R22); 8-phase 256x256 port (R28 -37%: 1 blk/CU,
// MfmaUtil 16 — graft lacks template's fine interleave); setprio (R15);
// VALU hoist (R14 null). This 2-phase config is the verified optimum.
// EPI: 1 = gelu(+bias) -> fp16 ; 2 = +bias+resid -> fp32
// ============================================================================
template<int EPI>
__global__ __launch_bounds__(256, 4) void gemm_1t(
    const u16* __restrict__ A, const u16* __restrict__ B,
    const float* __restrict__ bias, const float* __restrict__ resid,
    float* __restrict__ Cf, u16* __restrict__ Ch,
    int M, int N, int K)
{
    __shared__ u16 lds[2][2][4096];
    const int tid = threadIdx.x;
    const int l = tid & 63, w = tid >> 6;
    const int wr = (w >> 1) * 64, wc = (w & 1) * 64;
    int bx = blockIdx.x, by = blockIdx.y;
    xcd_swizzle(bx, by);
    const int row0 = by * 128, col0 = bx * 128;

    const int sg = w * 2;
    const int tl0 = sg * 16 + (l >> 2);
    const int tl1 = tl0 + 16;
    const int kq0 = (l & 3) ^ ((tl0 >> 1) & 3);
    const int kq1 = (l & 3) ^ ((tl1 >> 1) & 3);
    int ga0 = row0 + tl0; if (ga0 > M - 1) ga0 = M - 1;
    int ga1 = row0 + tl1; if (ga1 > M - 1) ga1 = M - 1;
    int gb0 = col0 + tl0; if (gb0 > N - 1) gb0 = N - 1;
    int gb1 = col0 + tl1; if (gb1 > N - 1) gb1 = N - 1;
    const u16* pA0 = A + (size_t)ga0 * K + kq0 * 8;
    const u16* pA1 = A + (size_t)ga1 * K + kq1 * 8;
    const u16* pB0 = B + (size_t)gb0 * K + kq0 * 8;
    const u16* pB1 = B + (size_t)gb1 * K + kq1 * 8;

    int offA[4], offB[4];
#pragma unroll
    for (int i = 0; i < 4; i++) {
        int ra = wr + i * 16 + (l & 15);
        offA[i] = ra * 32 + (((l >> 4) ^ ((ra >> 1) & 3)) << 3);
        int rb = wc + i * 16 + (l & 15);
        offB[i] = rb * 32 + (((l >> 4) ^ ((rb >> 1) & 3)) << 3);
    }

    f32x4 acc[4][4];
#pragma unroll
    for (int i = 0; i < 4; i++)
#pragma unroll
        for (int j = 0; j < 4; j++)
            acc[i][j] = (f32x4){0.f, 0.f, 0.f, 0.f};

    auto STAGE = [&](int buf, int kk) {
        gld_lds16(pA0 + kk, &lds[buf][0][(sg + 0) * 512]);
        gld_lds16(pA1 + kk, &lds[buf][0][(sg + 1) * 512]);
        gld_lds16(pB0 + kk, &lds[buf][1][(sg + 0) * 512]);
        gld_lds16(pB1 + kk, &lds[buf][1][(sg + 1) * 512]);
    };
    auto COMPUTE = [&](int buf) {
        f16x8 af[4], bf4[4];
#pragma unroll
        for (int i = 0; i < 4; i++) af[i] = *(const f16x8*)(&lds[buf][0][offA[i]]);
#pragma unroll
        for (int j = 0; j < 4; j++) bf4[j] = *(const f16x8*)(&lds[buf][1][offB[j]]);
#pragma unroll
        for (int i = 0; i < 4; i++)
#pragma unroll
            for (int j = 0; j < 4; j++)
                acc[i][j] = __builtin_amdgcn_mfma_f32_16x16x32_f16(af[i], bf4[j], acc[i][j], 0, 0, 0);
    };

    const int nk = K / 32;   // even for all our K
    STAGE(0, 0);
    __syncthreads();
    for (int t = 0; t < nk; t += 2) {
        if (t + 1 < nk) STAGE(1, (t + 1) * 32);
        COMPUTE(0);
        __syncthreads();
        if (t + 2 < nk) STAGE(0, (t + 2) * 32);
        COMPUTE(1);
        __syncthreads();
    }

    const int rq = l >> 4;
#pragma unroll
    for (int i = 0; i < 4; i++) {
#pragma unroll
        for (int j = 0; j < 4; j++) {
            int col = col0 + wc + j * 16 + (l & 15);
            float bs = bias[col];
#pragma unroll
            for (int r = 0; r < 4; r++) {
                int rowg = row0 + wr + i * 16 + rq * 4 + r;
                if (rowg >= M) continue;
                float vv = acc[i][j][r] + bs;
                size_t o = (size_t)rowg * N + col;
                if (EPI == 1) {
                    float gl = 0.5f * vv * (1.f + erff(vv * 0.70710678118654752f));
                    Ch[o] = f2h(gl);
                } else if (EPI == 2) {
                    Cf[o] = vv + resid[o];
                } else {
                    Cf[o] = vv;
                }
            }
        }
    }
}

// ============================================================================
// 256x128-tile fp16 GEMM, 512 threads / 8 waves, (512,4) cap (R25: validated,
// time-neutral vs 128x128 but halves A-fetch). Used for MLP1.
// EPI: 1 = gelu(+bias) -> fp16 ; 2 = +bias+resid -> fp32
// ============================================================================
template<int EPI>
__global__ __launch_bounds__(512, 4) void gemm_256(
    const u16* __restrict__ A, const u16* __restrict__ B,
    const float* __restrict__ bias, const float* __restrict__ resid,
    float* __restrict__ Cf, u16* __restrict__ Ch,
    int M, int N, int K)
{
    __shared__ u16 ldsA[2][256 * 32];   // [dbuf][row*32 + k]
    __shared__ u16 ldsB[2][128 * 32];
    const int tid = threadIdx.x;
    const int l = tid & 63, w = tid >> 6;          // w = 0..7
    const int wr = (w >> 1) * 64, wc = (w & 1) * 64;  // 4x2 wave grid
    int bx = blockIdx.x, by = blockIdx.y;
    xcd_swizzle(bx, by);
    const int row0 = by * 256, col0 = bx * 128;

    // A staging: wave w -> segments 2w, 2w+1 (16 rows each, 256 total)
    const int sgA = w * 2;
    const int tlA0 = sgA * 16 + (l >> 2);
    const int tlA1 = tlA0 + 16;
    const int kqA0 = (l & 3) ^ ((tlA0 >> 1) & 3);
    const int kqA1 = (l & 3) ^ ((tlA1 >> 1) & 3);
    int gaA0 = row0 + tlA0; if (gaA0 > M - 1) gaA0 = M - 1;
    int gaA1 = row0 + tlA1; if (gaA1 > M - 1) gaA1 = M - 1;
    const u16* pA0 = A + (size_t)gaA0 * K + kqA0 * 8;
    const u16* pA1 = A + (size_t)gaA1 * K + kqA1 * 8;
    // B staging: wave w -> segment w (16 rows, 128 total)
    const int tlB = w * 16 + (l >> 2);
    const int kqB = (l & 3) ^ ((tlB >> 1) & 3);
    int gbB = col0 + tlB; if (gbB > N - 1) gbB = N - 1;
    const u16* pB = B + (size_t)gbB * K + kqB * 8;

    int offA[4], offB[4];
#pragma unroll
    for (int i = 0; i < 4; i++) {
        int ra = wr + i * 16 + (l & 15);
        offA[i] = ra * 32 + (((l >> 4) ^ ((ra >> 1) & 3)) << 3);
        int rb = wc + i * 16 + (l & 15);
        offB[i] = rb * 32 + (((l >> 4) ^ ((rb >> 1) & 3)) << 3);
    }

    f32x4 acc[4][4];
#pragma unroll
    for (int i = 0; i < 4; i++)
#pragma unroll
        for (int j = 0; j < 4; j++)
            acc[i][j] = (f32x4){0.f, 0.f, 0.f, 0.f};

    auto STAGE = [&](int buf, int kk) {
        gld_lds16(pA0 + kk, &ldsA[buf][(sgA + 0) * 512]);
        gld_lds16(pA1 + kk, &ldsA[buf][(sgA + 1) * 512]);
        gld_lds16(pB + kk, &ldsB[buf][w * 512]);
    };
    auto COMPUTE = [&](int buf) {
        f16x8 af[4], bf4[4];
#pragma unroll
        for (int i = 0; i < 4; i++) af[i] = *(const f16x8*)(&ldsA[buf][offA[i]]);
#pragma unroll
        for (int j = 0; j < 4; j++) bf4[j] = *(const f16x8*)(&ldsB[buf][offB[j]]);
#pragma unroll
        for (int i = 0; i < 4; i++)
#pragma unroll
            for (int j = 0; j < 4; j++)
                acc[i][j] = __builtin_amdgcn_mfma_f32_16x16x32_f16(af[i], bf4[j], acc[i][j], 0, 0, 0);
    };

    const int nk = K / 32;   // even
    STAGE(0, 0);
    __syncthreads();
    for (int t = 0; t < nk; t += 2) {
        if (t + 1 < nk) STAGE(1, (t + 1) * 32);
        COMPUTE(0);
        __syncthreads();
        if (t + 2 < nk) STAGE(0, (t + 2) * 32);
        COMPUTE(1);
        __syncthreads();
    }

    const int rq = l >> 4;
#pragma unroll
    for (int i = 0; i < 4; i++) {
#pragma unroll
        for (int j = 0; j < 4; j++) {
            int col = col0 + wc + j * 16 + (l & 15);
            float bs = bias[col];
#pragma unroll
            for (int r = 0; r < 4; r++) {
                int rowg = row0 + wr + i * 16 + rq * 4 + r;
                if (rowg >= M) continue;
                float vv = acc[i][j][r] + bs;
                size_t o = (size_t)rowg * N + col;
                if (EPI == 1) {
                    float gl = 0.5f * vv * (1.f + erff(vv * 0.70710678118654752f));
                    Ch[o] = f2h(gl);
                } else if (EPI == 2) {
                    Cf[o] = vv + resid[o];
                } else {
                    Cf[o] = vv;
                }
            }
        }
    }
}

// ============================================================================
// Fused QKV GEMM (fp16), proven structure.
// Epilogue: q (x0.125 -> qb), k -> kb, v -> transposed vtb.
// ============================================================================
__global__ __launch_bounds__(256, 4) void gemm_qkv(
    const u16* __restrict__ A, const u16* __restrict__ B,
    const float* __restrict__ bq, const float* __restrict__ bk,
    const float* __restrict__ bv,
    u16* __restrict__ qb, u16* __restrict__ kb, u16* __restrict__ vt,
    int M, int N, int K)
{
    __shared__ u16 lds[2][2][4096];
    const int tid = threadIdx.x;
    const int l = tid & 63, w = tid >> 6;
    const int wr = (w >> 1) * 64, wc = (w & 1) * 64;
    int bx = blockIdx.x, by = blockIdx.y;
    xcd_swizzle(bx, by);
    const int row0 = by * 128, col0 = bx * 128;

    const int sg = w * 2;
    const int tl0 = sg * 16 + (l >> 2);
    const int tl1 = tl0 + 16;
    const int kq0 = (l & 3) ^ ((tl0 >> 1) & 3);
    const int kq1 = (l & 3) ^ ((tl1 >> 1) & 3);
    int ga0 = row0 + tl0; if (ga0 > M - 1) ga0 = M - 1;
    int ga1 = row0 + tl1; if (ga1 > M - 1) ga1 = M - 1;
    int gb0 = col0 + tl0; if (gb0 > N - 1) gb0 = N - 1;
    int gb1 = col0 + tl1; if (gb1 > N - 1) gb1 = N - 1;
    const u16* pA0 = A + (size_t)ga0 * K + kq0 * 8;
    const u16* pA1 = A + (size_t)ga1 * K + kq1 * 8;
    const u16* pB0 = B + (size_t)gb0 * K + kq0 * 8;
    const u16* pB1 = B + (size_t)gb1 * K + kq1 * 8;

    int offA[4], offB[4];
#pragma unroll
    for (int i = 0; i < 4; i++) {
        int ra = wr + i * 16 + (l & 15);
        offA[i] = ra * 32 + (((l >> 4) ^ ((ra >> 1) & 3)) << 3);
        int rb = wc + i * 16 + (l & 15);
        offB[i] = rb * 32 + (((l >> 4) ^ ((rb >> 1) & 3)) << 3);
    }

    f32x4 acc[4][4];
#pragma unroll
    for (int i = 0; i < 4; i++)
#pragma unroll
        for (int j = 0; j < 4; j++)
            acc[i][j] = (f32x4){0.f, 0.f, 0.f, 0.f};

    auto STAGE = [&](int buf, int kk) {
        gld_lds16(pA0 + kk, &lds[buf][0][(sg + 0) * 512]);
        gld_lds16(pA1 + kk, &lds[buf][0][(sg + 1) * 512]);
        gld_lds16(pB0 + kk, &lds[buf][1][(sg + 0) * 512]);
        gld_lds16(pB1 + kk, &lds[buf][1][(sg + 1) * 512]);
    };
    auto COMPUTE = [&](int buf) {
        f16x8 af[4], bf4[4];
#pragma unroll
        for (int i = 0; i < 4; i++) af[i] = *(const f16x8*)(&lds[buf][0][offA[i]]);
#pragma unroll
        for (int j = 0; j < 4; j++) bf4[j] = *(const f16x8*)(&lds[buf][1][offB[j]]);
#pragma unroll
        for (int i = 0; i < 4; i++)
#pragma unroll
            for (int j = 0; j < 4; j++)
                acc[i][j] = __builtin_amdgcn_mfma_f32_16x16x32_f16(af[i], bf4[j], acc[i][j], 0, 0, 0);
    };

    const int nk = K / 32;
    STAGE(0, 0);
    __syncthreads();
    for (int t = 0; t < nk; t += 2) {
        if (t + 1 < nk) STAGE(1, (t + 1) * 32);
        COMPUTE(0);
        __syncthreads();
        if (t + 2 < nk) STAGE(0, (t + 2) * 32);
        COMPUTE(1);
        __syncthreads();
    }

    const int rq = l >> 4;
#pragma unroll
    for (int i = 0; i < 4; i++) {
#pragma unroll
        for (int j = 0; j < 4; j++) {
            int col = col0 + wc + j * 16 + (l & 15);
#pragma unroll
            for (int r = 0; r < 4; r++) {
                int rowg = row0 + wr + i * 16 + rq * 4 + r;
                if (rowg >= M) continue;
                float a = acc[i][j][r];
                if (col < 1024) {
                    qb[(size_t)rowg * 1024 + col] = f2h((a + bq[col]) * 0.125f);
                } else if (col < 2048) {
                    int c2 = col - 1024;
                    kb[(size_t)rowg * 1024 + c2] = f2h(a + bk[c2]);
                } else {
                    int c2 = col - 2048;
                    u32 rg = (u32)rowg;
                    u32 bb = rg / 577u;
                    u32 key = rg - bb * 577u;
                    vt[((size_t)((bb * 16 + (c2 >> 6)) * 64 + (c2 & 63))) * 640 + key] =
                        f2h(a + bv[c2]);
                }
            }
        }
    }
}

// ============================================================================
// MFMA flash attention (fp16 operands, fp32 accum). Output: fp16 ctx.
// K/V LDS tiles XOR-swizzled; R27 T14 reg-staged prefetch (kept, neutral).
// ============================================================================
__global__ __launch_bounds__(256) void flash_mfma(const u16* __restrict__ Qg,
                                                  const u16* __restrict__ Kg,
                                                  const u16* __restrict__ Vt,
                                                  u16* __restrict__ Oh) {
    __shared__ u16 Kl[64 * 64];     // [key][dh], 16B slots swizzled
    __shared__ u16 Vl[64 * 64];     // [d][key], 16B slots swizzled
    __shared__ u16 Pl[64][72];      // wave-private 16-row stripes, padded

    int bx = blockIdx.x, by = blockIdx.y;
    xcd_swizzle(bx, by);
    const int qt = bx, bh = by;
    const int b = bh >> 4, h = bh & 15;
    const int tid = threadIdx.x;
    const int l = tid & 63, w = tid >> 6;
    const int q0 = qt * 64;

    int qrow = q0 + w * 16 + (l & 15); if (qrow > 576) qrow = 576;
    const u16* qp = Qg + ((size_t)(b * 577 + qrow)) * 1024 + h * 64 + (l >> 4) * 8;
    f16x8 qf0 = *(const f16x8*)qp;
    f16x8 qf1 = *(const f16x8*)(qp + 32);

    const int swk = ((l & 7) ^ (l >> 3)) * 8;

    f32x4 ctx[4];
#pragma unroll
    for (int d = 0; d < 4; d++) ctx[d] = (f32x4){0.f, 0.f, 0.f, 0.f};
    float m_r[4], l_r[4];
#pragma unroll
    for (int r = 0; r < 4; r++) { m_r[r] = -1e30f; l_r[r] = 0.f; }

    // prologue: stage tile 0 via global_load_lds
#pragma unroll
    for (int c2 = 0; c2 < 2; ++c2) {
        int c = w * 2 + c2;
        int key = c * 8 + (l >> 3); if (key > 576) key = 576;
        const u16* ksrc = Kg + ((size_t)(b * 577 + key)) * 1024 + h * 64 + swk;
        gld_lds16(ksrc, Kl + c * 512);
        int d = c * 8 + (l >> 3);
        const u16* vsrc = Vt + ((size_t)(bh * 64 + d)) * 640 + swk;
        gld_lds16(vsrc, Vl + c * 512);
    }
    __syncthreads();

    for (int kt = 0; kt < 10; ++kt) {
        f16x8 kreg[2], vreg[2];
        if (kt < 9) {
            const int kb2 = (kt + 1) * 64;
#pragma unroll
            for (int c2 = 0; c2 < 2; ++c2) {
                int c = w * 2 + c2;
                int key = kb2 + c * 8 + (l >> 3); if (key > 576) key = 576;
                kreg[c2] = *(const f16x8*)(Kg + ((size_t)(b * 577 + key)) * 1024 + h * 64 + swk);
                int d = c * 8 + (l >> 3);
                vreg[c2] = *(const f16x8*)(Vt + ((size_t)(bh * 64 + d)) * 640 + kb2 + swk);
            }
        }

        const int kb = kt * 64;
        f32x4 sc[4];
#pragma unroll
        for (int sub = 0; sub < 4; ++sub) {
            sc[sub] = (f32x4){0.f, 0.f, 0.f, 0.f};
            int rr = sub * 16 + (l & 15);
            int c0 = (l >> 4) ^ (rr & 7);
            int c1 = ((l >> 4) + 4) ^ (rr & 7);
            f16x8 kf0 = *(const f16x8*)(Kl + rr * 64 + c0 * 8);
            f16x8 kf1 = *(const f16x8*)(Kl + rr * 64 + c1 * 8);
            sc[sub] = __builtin_amdgcn_mfma_f32_16x16x32_f16(qf0, kf0, sc[sub], 0, 0, 0);
            sc[sub] = __builtin_amdgcn_mfma_f32_16x16x32_f16(qf1, kf1, sc[sub], 0, 0, 0);
        }

        bool valid[4];
#pragma unroll
        for (int sub = 0; sub < 4; ++sub) valid[sub] = (kb + sub * 16 + (l & 15)) < Sn;

#pragma unroll
        for (int r = 0; r < 4; ++r) {
            float s0 = valid[0] ? sc[0][r] : -1e30f;
            float s1 = valid[1] ? sc[1][r] : -1e30f;
            float s2 = valid[2] ? sc[2][r] : -1e30f;
            float s3 = valid[3] ? sc[3][r] : -1e30f;
            float mx = fmaxf(fmaxf(s0, s1), fmaxf(s2, s3));
            mx = fmaxf(mx, __shfl_xor(mx, 1));
            mx = fmaxf(mx, __shfl_xor(mx, 2));
            mx = fmaxf(mx, __shfl_xor(mx, 4));
            mx = fmaxf(mx, __shfl_xor(mx, 8));
            float mnew = fmaxf(m_r[r], mx);
            float scale = __expf(m_r[r] - mnew);
            float p0 = valid[0] ? __expf(s0 - mnew) : 0.f;
            float p1 = valid[1] ? __expf(s1 - mnew) : 0.f;
            float p2 = valid[2] ? __expf(s2 - mnew) : 0.f;
            float p3 = valid[3] ? __expf(s3 - mnew) : 0.f;
            int prow = w * 16 + (l >> 4) * 4 + r;
            int pcol = l & 15;
            Pl[prow][pcol]      = f2h(p0);
            Pl[prow][pcol + 16] = f2h(p1);
            Pl[prow][pcol + 32] = f2h(p2);
            Pl[prow][pcol + 48] = f2h(p3);
            float rsum = p0 + p1 + p2 + p3;
            rsum += __shfl_xor(rsum, 1);
            rsum += __shfl_xor(rsum, 2);
            rsum += __shfl_xor(rsum, 4);
            rsum += __shfl_xor(rsum, 8);
            l_r[r] = l_r[r] * scale + rsum;
            m_r[r] = mnew;
#pragma unroll
            for (int d = 0; d < 4; ++d) ctx[d][r] *= scale;
        }

#pragma unroll
        for (int ks = 0; ks < 2; ++ks) {
            f16x8 pf = *(const f16x8*)(&Pl[w * 16 + (l & 15)][ks * 32 + (l >> 4) * 8]);
#pragma unroll
            for (int d = 0; d < 4; ++d) {
                int rr = d * 16 + (l & 15);
                int cv = (ks * 4 + (l >> 4)) ^ (rr & 7);
                f16x8 vf = *(const f16x8*)(Vl + rr * 64 + cv * 8);
                ctx[d] = __builtin_amdgcn_mfma_f32_16x16x32_f16(pf, vf, ctx[d], 0, 0, 0);
            }
        }
        __syncthreads();

        if (kt < 9) {
#pragma unroll
            for (int c2 = 0; c2 < 2; ++c2) {
                int c = w * 2 + c2;
                *(f16x8*)(Kl + c * 512 + l * 8) = kreg[c2];
                *(f16x8*)(Vl + c * 512 + l * 8) = vreg[c2];
            }
            __syncthreads();
        }
    }

#pragma unroll
    for (int r = 0; r < 4; ++r) {
        int q = q0 + w * 16 + (l >> 4) * 4 + r;
        if (q >= Sn) continue;
        float inv = 1.f / l_r[r];
#pragma unroll
        for (int d = 0; d < 4; ++d) {
            float t = ctx[d][r] * inv;
            size_t o = ((size_t)(b * 577 + q)) * 1024 + h * 64 + d * 16 + (l & 15);
            Oh[o] = f2h(t);
        }
    }
}

// ============================================================================
// fp32 tiled GEMM (fallback path only)
// ============================================================================
template<int EPI>
__global__ __launch_bounds__(256) void gemm_kernel(const float* __restrict__ A,
                                                   const float* __restrict__ W,
                                                   const float* __restrict__ bias,
                                                   const float* __restrict__ resid,
                                                   float* __restrict__ C,
                                                   int M, int N, int K) {
    const int BM = 64, BN = 64, BK = 16;
    __shared__ float As[BK][BM + 1];
    __shared__ float Ws[BK][BN];
    int tx = threadIdx.x, ty = threadIdx.y;
    int tid = ty * 16 + tx;
    int row0 = blockIdx.y * BM, col0 = blockIdx.x * BN;
    float acc[4][4] = {};
    for (int k0 = 0; k0 < K; k0 += BK) {
#pragma unroll
        for (int i = 0; i < 4; i++) {
            int idx = i * 256 + tid;
            int ar = idx >> 4, ac = idx & 15;
            int grow = row0 + ar;
            As[ac][ar] = (grow < M) ? A[(size_t)grow * K + k0 + ac] : 0.f;
        }
#pragma unroll
        for (int i = 0; i < 4; i++) {
            int idx = i * 256 + tid;
            int wr = idx >> 6, wcc = idx & 63;
            Ws[wr][wcc] = W[(size_t)(k0 + wr) * N + col0 + wcc];
        }
        __syncthreads();
#pragma unroll
        for (int kk = 0; kk < BK; kk++) {
            float a[4], wv[4];
#pragma unroll
            for (int i = 0; i < 4; i++) a[i] = As[kk][ty * 4 + i];
#pragma unroll
            for (int j = 0; j < 4; j++) wv[j] = Ws[kk][tx * 4 + j];
#pragma unroll
            for (int i = 0; i < 4; i++)
#pragma unroll
                for (int j = 0; j < 4; j++)
                    acc[i][j] += a[i] * wv[j];
        }
        __syncthreads();
    }
#pragma unroll
    for (int i = 0; i < 4; i++) {
        int grow = row0 + ty * 4 + i;
        if (grow >= M) continue;
#pragma unroll
        for (int j = 0; j < 4; j++) {
            int gcol = col0 + tx * 4 + j;
            float r = acc[i][j] + bias[gcol];
            if (EPI == 1) r = 0.5f * r * (1.f + erff(r * 0.70710678118654752f));
            if (EPI == 2) r += resid[(size_t)grow * N + gcol];
            C[(size_t)grow * N + gcol] = r;
        }
    }
}

// ============================================================================
// fp32 flash attention (fallback path only)
// ============================================================================
__global__ __launch_bounds__(256) void flash_kernel(const float* __restrict__ Q,
                                                    const float* __restrict__ K,
                                                    const float* __restrict__ V,
                                                    float* __restrict__ Of) {
    __shared__ float Qs[64][68];
    __shared__ float KT[64][68];
    __shared__ float Vs[64][68];
    __shared__ float Ps[64][68];

    int qt = blockIdx.x;
    int bh = blockIdx.y;
    int b = bh >> 4, h = bh & 15;
    int tid = threadIdx.x;
    int tx = tid & 15, ty = tid >> 4;
    size_t base = ((size_t)b * Sn) * Dn + (size_t)h * DHn;
    int q0 = qt * 64;

    {
        int r = tid >> 4;
        int c = (tid & 15) * 4;
#pragma unroll
        for (int i = 0; i < 4; i++) {
            int rr = r + i * 16;
            int gq = q0 + rr;
            float4 val = make_float4(0.f, 0.f, 0.f, 0.f);
            if (gq < Sn) val = *(const float4*)&Q[base + (size_t)gq * Dn + c];
            Qs[rr][c + 0] = val.x * 0.125f;
            Qs[rr][c + 1] = val.y * 0.125f;
            Qs[rr][c + 2] = val.z * 0.125f;
            Qs[rr][c + 3] = val.w * 0.125f;
        }
    }

    float m_r[4], l_r[4], acc[4][4];
#pragma unroll
    for (int i = 0; i < 4; i++) {
        m_r[i] = -1e30f; l_r[i] = 0.f;
#pragma unroll
        for (int j = 0; j < 4; j++) acc[i][j] = 0.f;
    }

    for (int kt = 0; kt < 10; kt++) {
        int kb = kt * 64;
        {
            int r = tid >> 4;
            int c = (tid & 15) * 4;
#pragma unroll
            for (int i = 0; i < 4; i++) {
                int rr = r + i * 16;
                int gk = kb + rr;
                float4 kv = make_float4(0.f, 0.f, 0.f, 0.f);
                float4 vv = make_float4(0.f, 0.f, 0.f, 0.f);
                if (gk < Sn) {
                    kv = *(const float4*)&K[base + (size_t)gk * Dn + c];
                    vv = *(const float4*)&V[base + (size_t)gk * Dn + c];
                }
                KT[c + 0][rr] = kv.x;
                KT[c + 1][rr] = kv.y;
                KT[c + 2][rr] = kv.z;
                KT[c + 3][rr] = kv.w;
                Vs[rr][c + 0] = vv.x;
                Vs[rr][c + 1] = vv.y;
                Vs[rr][c + 2] = vv.z;
                Vs[rr][c + 3] = vv.w;
            }
        }
        __syncthreads();

        float s[4][4] = {};
#pragma unroll
        for (int kk4 = 0; kk4 < 16; kk4++) {
            float4 a4[4], b4[4];
#pragma unroll
            for (int i = 0; i < 4; i++) a4[i] = *(const float4*)&Qs[ty * 4 + i][kk4 * 4];
#pragma unroll
            for (int q = 0; q < 4; q++) b4[q] = *(const float4*)&KT[kk4 * 4 + q][tx * 4];
#pragma unroll
            for (int i = 0; i < 4; i++) {
                float av[4] = {a4[i].x, a4[i].y, a4[i].z, a4[i].w};
#pragma unroll
                for (int q = 0; q < 4; q++) {
                    s[i][0] += av[q] * b4[q].x;
                    s[i][1] += av[q] * b4[q].y;
                    s[i][2] += av[q] * b4[q].z;
                    s[i][3] += av[q] * b4[q].w;
                }
            }
        }

        bool cvalid[4];
#pragma unroll
        for (int j = 0; j < 4; j++) cvalid[j] = (kb + tx * 4 + j) < Sn;
#pragma unroll
        for (int i = 0; i < 4; i++) {
            float lmax = -1e30f;
#pragma unroll
            for (int j = 0; j < 4; j++) if (cvalid[j]) lmax = fmaxf(lmax, s[i][j]);
            lmax = fmaxf(lmax, __shfl_xor(lmax, 1));
            lmax = fmaxf(lmax, __shfl_xor(lmax, 2));
            lmax = fmaxf(lmax, __shfl_xor(lmax, 4));
            lmax = fmaxf(lmax, __shfl_xor(lmax, 8));
            float mnew = fmaxf(m_r[i], lmax);
            float scale = __expf(m_r[i] - mnew);
            float rsum = 0.f;
#pragma unroll
            for (int j = 0; j < 4; j++) {
                float p = cvalid[j] ? __expf(s[i][j] - mnew) : 0.f;
                s[i][j] = p;
                rsum += p;
            }
            rsum += __shfl_xor(rsum, 1);
            rsum += __shfl_xor(rsum, 2);
            rsum += __shfl_xor(rsum, 4);
            rsum += __shfl_xor(rsum, 8);
            l_r[i] = l_r[i] * scale + rsum;
            m_r[i] = mnew;
#pragma unroll
            for (int j = 0; j < 4; j++) acc[i][j] *= scale;
        }

#pragma unroll
        for (int i = 0; i < 4; i++)
#pragma unroll
            for (int j = 0; j < 4; j++)
                Ps[ty * 4 + i][tx * 4 + j] = s[i][j];
        __syncthreads();

#pragma unroll
        for (int kk4 = 0; kk4 < 16; kk4++) {
            float4 a4[4], b4[4];
#pragma unroll
            for (int i = 0; i < 4; i++) a4[i] = *(const float4*)&Ps[ty * 4 + i][kk4 * 4];
#pragma unroll
            for (int q = 0; q < 4; q++) b4[q] = *(const float4*)&Vs[kk4 * 4 + q][tx * 4];
#pragma unroll
            for (int i = 0; i < 4; i++) {
                float av[4] = {a4[i].x, a4[i].y, a4[i].z, a4[i].w};
#pragma unroll
                for (int q = 0; q < 4; q++) {
                    acc[i][0] += av[q] * b4[q].x;
                    acc[i][1] += av[q] * b4[q].y;
                    acc[i][2] += av[q] * b4[q].z;
                    acc[i][3] += av[q] * b4[q].w;
                }
            }
        }
        __syncthreads();
    }

#pragma unroll
    for (int i = 0; i < 4; i++) {
        int gq = q0 + ty * 4 + i;
        if (gq >= Sn) continue;
        float inv = 1.f / l_r[i];
#pragma unroll
        for (int j = 0; j < 4; j++)
            Of[base + (size_t)gq * Dn + tx * 4 + j] = acc[i][j] * inv;
    }
}

// ============================================================================
extern "C" void kernel_launch(void* const* d_in, const int* in_sizes, int n_in,
                              void* d_out, int out_size, void* d_ws, size_t ws_size,
                              hipStream_t stream) {
    const float* x    = (const float*)d_in[0];
    const float* ln1g = (const float*)d_in[1];
    const float* ln1b = (const float*)d_in[2];
    const float* wq   = (const float*)d_in[3];
    const float* bq   = (const float*)d_in[4];
    const float* wk   = (const float*)d_in[5];
    const float* bk   = (const float*)d_in[6];
    const float* wv   = (const float*)d_in[7];
    const float* bv   = (const float*)d_in[8];
    const float* wo   = (const float*)d_in[9];
    const float* bo   = (const float*)d_in[10];
    const float* ln2g = (const float*)d_in[11];
    const float* ln2b = (const float*)d_in[12];
    const float* w1   = (const float*)d_in[13];
    const float* b1   = (const float*)d_in[14];
    const float* w2   = (const float*)d_in[15];
    const float* b2   = (const float*)d_in[16];
    float* out = (float*)d_out;
    char* ws = (char*)d_ws;

    const size_t WHALF_D = (size_t)1024 * 1024 * 2;   // 2 MB
    const size_t WHALF_F = (size_t)4096 * 1024 * 2;   // 8 MB
    const size_t HALF_XN = (size_t)NROW * 1024 * 2;   // 18,907,136
    const size_t BASE_A  = 8 * WHALF_D + 4 * WHALF_F; // 50,331,648 (weights)
    const size_t NEED = BASE_A + 10 * HALF_XN;        // 239,403,008

    if (ws_size >= NEED) {
        // -------- fp16 MFMA path --------
        u16* wqkvT = (u16*)(ws);                          // [0, 6MB) fused q|k|v
        u16* woT   = (u16*)(ws + 6 * WHALF_D);            // 2 MB
        u16* w1T   = (u16*)(ws + 8 * WHALF_D);            // 8 MB
        u16* w2T   = (u16*)(ws + 8 * WHALF_D + 2 * WHALF_F);
        char* S = ws + BASE_A;
        u16* xn_h  = (u16*)(S + 0 * HALF_XN);
        u16* qb    = (u16*)(S + 2 * HALF_XN);
        u16* kb2   = (u16*)(S + 3 * HALF_XN);
        u16* vtb   = (u16*)(S + 4 * HALF_XN);
        u16* ctx_h = (u16*)(S + 8 * HALF_XN);
        u16* xn2_h = (u16*)(S + 9 * HALF_XN);
        u16* hm_h  = (u16*)(S + 0 * HALF_XN);   // spans S0-3

        // R26: weight conversions + vtb zeroing + LN1 in ONE dispatch
        prep_all<<<22800, 256, 0, stream>>>(wq, wk, wv, wo, w1, w2,
                                            x, ln1g, ln1b,
                                            wqkvT, woT, w1T, w2T, vtb, xn_h);

        gemm_qkv<<<dim3(24, 73), 256, 0, stream>>>(xn_h, wqkvT, bq, bk, bv,
                                                   qb, kb2, vtb, NROW, 3072, 1024);
        flash_mfma<<<dim3(10, Bn * Hn), 256, 0, stream>>>(qb, kb2, vtb, ctx_h);
        // proj: +bias+resid -> fp32 out
        gemm_1t<2><<<dim3(8, 73), 256, 0, stream>>>(
            ctx_h, woT, bo, x, out, nullptr, NROW, 1024, 1024);
        ln_f16<<<NROW, 256, 0, stream>>>(out, ln2g, ln2b, xn2_h);
        // MLP1: gelu -> fp16 hm (256x128 tile @ (512,4), R25-validated)
        gemm_256<1><<<dim3(32, 37), 512, 0, stream>>>(
            xn2_h, w1T, b1, nullptr, nullptr, hm_h, NROW, 4096, 1024);
        // MLP2: +bias+resid -> fp32 out (proven 128x128)
        gemm_1t<2><<<dim3(8, 73), 256, 0, stream>>>(
            hm_h, w2T, b2, out, out, nullptr, NROW, 1024, 4096);
    } else {
        // -------- fp32 fallback path (proven) --------
        const size_t SZ = (size_t)NROW * Dn * sizeof(float);
        float* qbuf  = (float*)(ws);
        float* kbuf  = (float*)(ws + SZ);
        float* vbuf  = (float*)(ws + 2 * SZ);
        float* hmid  = (float*)(ws);
        float* xnbuf = (float*)(ws + 4 * SZ);
        float* ctx   = (float*)(ws + 5 * SZ);
        float* x1    = (float*)(ws + 6 * SZ);
        dim3 blk2(16, 16);
        dim3 gD(Dn / 64, (NROW + 63) / 64);
        dim3 gF(Fn / 64, (NROW + 63) / 64);
        ln_kernel<<<NROW, 256, 0, stream>>>(x, ln1g, ln1b, xnbuf);
        gemm_kernel<0><<<gD, blk2, 0, stream>>>(xnbuf, wq, bq, nullptr, qbuf, NROW, Dn, Dn);
        gemm_kernel<0><<<gD, blk2, 0, stream>>>(xnbuf, wk, bk, nullptr, kbuf, NROW, Dn, Dn);
        gemm_kernel<0><<<gD, blk2, 0, stream>>>(xnbuf, wv, bv, nullptr, vbuf, NROW, Dn, Dn);
        flash_kernel<<<dim3(10, Bn * Hn), 256, 0, stream>>>(qbuf, kbuf, vbuf, ctx);
        gemm_kernel<2><<<gD, blk2, 0, stream>>>(ctx, wo, bo, x, x1, NROW, Dn, Dn);
        ln_kernel<<<NROW, 256, 0, stream>>>(x1, ln2g, ln2b, xnbuf);
        gemm_kernel<1><<<gF, blk2, 0, stream>>>(xnbuf, w1, b1, nullptr, hmid, NROW, Fn, Dn);
        gemm_kernel<2><<<gD, blk2, 0, stream>>>(hmid, w2, b2, x1, out, NROW, Dn, Fn);
    }
}